// Round 5
// 354.375 us; speedup vs baseline: 1.0855x; 1.0855x over previous
//
#include <hip/hip_runtime.h>
#include <hip/hip_bf16.h>

// GCN 2-layer, fp32 I/O. Pipeline:
//   [both layers up front] bin_hist/scan/bin_scatter (bucket = dst>>8, layer-major
//        concatenated scan -> layer-2 records land at offset E automatically)
//        -> bucket_sort (in-LDS counting sort by dst&255 -> dst-sorted CSR + rowptr)
//   gemm1 (register-tiled fp32 -> bf16 h1, written over the dead recbuf region)
//   gather1 (wave-per-node, 8-wide ILP) FUSED with relu + gemm2 epilogue
//        (LDS-staged row dot W2 -> h2 directly; agg1 round-trip eliminated)
//   gather2 (wave-per-4-nodes, 8-wide ILP)
// Record int2: .x = src | (dst&255)<<20, .y = bits of w.

#define EPB 4096     // edges per binning block
#define NBMAX 512    // max buckets (N <= 131072)
#define CAP 6144     // max records per bucket (avg 4096; 32-sigma headroom)

// ---------------- dense layer 1 (register-tiled, k-major LDS) ----------------

// gemm1: [N,128] @ [128,64] -> bf16 [N,64]. 128 threads, tile 128n x 64f, thread 8x8.
__global__ __launch_bounds__(128) void gemm1_kernel(const float* __restrict__ x,
                                                    const float* __restrict__ W1,
                                                    __hip_bfloat16* __restrict__ h1,
                                                    int n_nodes) {
    __shared__ float As[32][132];   // k-major, node-contiguous; padded
    __shared__ float Bs[32][64];    // k-major, feat-contiguous
    int tid = threadIdx.x;
    int node0 = blockIdx.x * 128;
    int n8 = (tid & 15) * 8;
    int f8 = (tid >> 4) * 8;
    float acc[8][8];
#pragma unroll
    for (int i = 0; i < 8; ++i)
#pragma unroll
        for (int j = 0; j < 8; ++j) acc[i][j] = 0.f;

    const float4* x4 = reinterpret_cast<const float4*>(x);
    const float4* W4 = reinterpret_cast<const float4*>(W1);

    for (int s = 0; s < 4; ++s) {
#pragma unroll
        for (int j = 0; j < 8; ++j) {
            int idx = tid + j * 128;            // 1024 float4 = 128n x 32k
            int n = idx >> 3;
            int kq = idx & 7;
            float4 v = make_float4(0.f, 0.f, 0.f, 0.f);
            if (node0 + n < n_nodes) v = x4[(size_t)(node0 + n) * 32 + s * 8 + kq];
            int k4 = kq * 4;
            As[k4 + 0][n] = v.x;
            As[k4 + 1][n] = v.y;
            As[k4 + 2][n] = v.z;
            As[k4 + 3][n] = v.w;
        }
#pragma unroll
        for (int j = 0; j < 4; ++j) {
            int idx = tid + j * 128;            // 512 float4 = 32k x 64f
            int k = idx >> 4;
            int fq = idx & 15;
            *reinterpret_cast<float4*>(&Bs[k][fq * 4]) = W4[(size_t)(s * 32 + k) * 16 + fq];
        }
        __syncthreads();
#pragma unroll
        for (int kk = 0; kk < 32; ++kk) {
            float4 a0 = *reinterpret_cast<const float4*>(&As[kk][n8]);
            float4 a1 = *reinterpret_cast<const float4*>(&As[kk][n8 + 4]);
            float4 b0 = *reinterpret_cast<const float4*>(&Bs[kk][f8]);
            float4 b1 = *reinterpret_cast<const float4*>(&Bs[kk][f8 + 4]);
            float av[8] = {a0.x, a0.y, a0.z, a0.w, a1.x, a1.y, a1.z, a1.w};
            float bv[8] = {b0.x, b0.y, b0.z, b0.w, b1.x, b1.y, b1.z, b1.w};
#pragma unroll
            for (int i = 0; i < 8; ++i)
#pragma unroll
                for (int j = 0; j < 8; ++j) acc[i][j] += av[i] * bv[j];
        }
        __syncthreads();
    }
#pragma unroll
    for (int i = 0; i < 8; ++i) {
        int n = node0 + n8 + i;
        if (n < n_nodes) {
            __hip_bfloat16 tmp[8];
#pragma unroll
            for (int j = 0; j < 8; ++j) tmp[j] = __float2bfloat16(acc[i][j]);
            *reinterpret_cast<uint4*>(&h1[(size_t)n * 64 + f8]) =
                *reinterpret_cast<const uint4*>(tmp);
        }
    }
}

// ---------------- edge binning, BOTH layers in one pass (bucket = dst>>8) ---------
// hist layout: [layer][bucket][blk] flattened; a single exclusive scan over the
// concatenation yields global record positions in a 2E array: layer 1 in [0,E),
// layer 2 in [E,2E).

__global__ void bin_hist_kernel(const int* __restrict__ ei1, const int* __restrict__ ei2,
                                int* __restrict__ hist_g, int n_edges, int nblk, int nb) {
    __shared__ int hist[NBMAX];
    int tid = threadIdx.x, blk = blockIdx.x;
    int layer = (blk >= nblk) ? 1 : 0;
    int lblk = blk - layer * nblk;
    const int* ei = layer ? ei2 : ei1;
    for (int i = tid; i < nb; i += 256) hist[i] = 0;
    __syncthreads();
    int e0 = lblk * EPB;
#pragma unroll
    for (int j = 0; j < EPB / 256; ++j) {
        int e = e0 + tid + j * 256;
        if (e < n_edges) atomicAdd(&hist[ei[n_edges + e] >> 8], 1);
    }
    __syncthreads();
    int base = layer * nb * nblk;
    for (int i = tid; i < nb; i += 256) hist_g[base + i * nblk + lblk] = hist[i];
}

__global__ void scan_local_k(int* __restrict__ data, int* __restrict__ bsums, int n) {
    __shared__ int tmp[1024];
    int i = blockIdx.x * 1024 + threadIdx.x;
    int v = (i < n) ? data[i] : 0;
    tmp[threadIdx.x] = v;
    __syncthreads();
    for (int off = 1; off < 1024; off <<= 1) {
        int t = (threadIdx.x >= off) ? tmp[threadIdx.x - off] : 0;
        __syncthreads();
        tmp[threadIdx.x] += t;
        __syncthreads();
    }
    if (i < n) data[i] = tmp[threadIdx.x] - v;   // exclusive, in place
    if (threadIdx.x == 1023) bsums[blockIdx.x] = tmp[1023];
}

__global__ void scan_top_k(int* __restrict__ bsums, int nbk) {
    __shared__ int tmp[512];
    int v = (threadIdx.x < nbk) ? bsums[threadIdx.x] : 0;
    tmp[threadIdx.x] = v;
    __syncthreads();
    for (int off = 1; off < 512; off <<= 1) {
        int t = (threadIdx.x >= off) ? tmp[threadIdx.x - off] : 0;
        __syncthreads();
        tmp[threadIdx.x] += t;
        __syncthreads();
    }
    if (threadIdx.x < nbk) bsums[threadIdx.x] = tmp[threadIdx.x] - v;  // exclusive
}

__global__ void add_offsets_k(int* __restrict__ data, const int* __restrict__ bsums, int n) {
    int i = blockIdx.x * 1024 + threadIdx.x;
    if (i < n) data[i] += bsums[blockIdx.x];
}

__global__ void bin_scatter_kernel(const int* __restrict__ ei1, const int* __restrict__ ei2,
                                   const float* __restrict__ ew1, const float* __restrict__ ew2,
                                   const int* __restrict__ scan_g, int2* __restrict__ rec_out,
                                   int n_edges, int nblk, int nb) {
    __shared__ int2 srec[EPB];               // 32 KB
    __shared__ unsigned short sbkt[EPB];     // 8 KB
    __shared__ int loff[NBMAX], cur[NBMAX], gbase[NBMAX];  // 6 KB
    __shared__ int p[256];
    int tid = threadIdx.x, blk = blockIdx.x;
    int layer = (blk >= nblk) ? 1 : 0;
    int lblk = blk - layer * nblk;
    const int* ei = layer ? ei2 : ei1;
    const float* ew = layer ? ew2 : ew1;
    int n_scan_tot = 2 * nb * nblk;
    int total = 2 * n_edges;
    int base = layer * nb * nblk;
    int e0 = lblk * EPB;
    int cnt = min(EPB, n_edges - e0);
    // per-bucket counts for this block, reconstructed from adjacent scan entries
    for (int i = tid; i < nb; i += 256) {
        int l = base + i * nblk + lblk;
        int g = scan_g[l];
        int nxt = (l + 1 < n_scan_tot) ? scan_g[l + 1] : total;
        gbase[i] = g;
        loff[i] = nxt - g;                    // temporarily holds count
    }
    __syncthreads();
    // exclusive scan of counts -> loff (2 buckets/thread + Hillis-Steele over partials)
    int b0 = tid * 2;
    int c0 = (b0 < nb) ? loff[b0] : 0;
    int c1 = (b0 + 1 < nb) ? loff[b0 + 1] : 0;
    p[tid] = c0 + c1;
    __syncthreads();
    for (int off = 1; off < 256; off <<= 1) {
        int t = (tid >= off) ? p[tid - off] : 0;
        __syncthreads();
        p[tid] += t;
        __syncthreads();
    }
    int pbase = (tid > 0) ? p[tid - 1] : 0;
    __syncthreads();
    if (b0 < nb)     { loff[b0] = pbase;          cur[b0] = pbase; }
    if (b0 + 1 < nb) { loff[b0 + 1] = pbase + c0; cur[b0 + 1] = pbase + c0; }
    __syncthreads();
    // rank + stage (LDS counting sort by bucket)
#pragma unroll
    for (int j = 0; j < EPB / 256; ++j) {
        int e = e0 + tid + j * 256;
        if (e < n_edges) {
            int s = ei[e], d = ei[n_edges + e];
            int b = d >> 8;
            int r = atomicAdd(&cur[b], 1);
            srec[r] = make_int2(s | ((d & 255) << 20), __float_as_int(ew[e]));
            sbkt[r] = (unsigned short)b;
        }
    }
    __syncthreads();
    // coalesced run writes
    for (int i = tid; i < cnt; i += 256) {
        int b = sbkt[i];
        rec_out[gbase[b] + (i - loff[b])] = srec[i];
    }
}

// ---------------- per-bucket node sort (-> full CSR + rowptr, both layers) -------

__global__ __launch_bounds__(256) void bucket_sort_kernel(
        const int2* __restrict__ rec_in, const int* __restrict__ scan_g,
        int2* __restrict__ rec_out, int* __restrict__ rowptr1, int* __restrict__ rowptr2,
        int n_nodes, int n_edges, int nblk, int nb) {
    __shared__ int2 srec[CAP];               // 48 KB
    __shared__ int hist[256], cur[256], rp[256];
    int tid = threadIdx.x, b = blockIdx.x;   // global bucket id in [0, 2*nb)
    int layer = (b >= nb) ? 1 : 0;
    int lb = b - layer * nb;
    int* rowptr = layer ? rowptr2 : rowptr1;
    int total = 2 * n_edges;
    int start = scan_g[b * nblk];
    int end = (b + 1 < 2 * nb) ? scan_g[(b + 1) * nblk] : total;
    int cnt = end - start;
    hist[tid] = 0;
    __syncthreads();
    for (int i = tid; i < cnt; i += 256) {
        int2 r = rec_in[start + i];
        atomicAdd(&hist[(r.x >> 20) & 255], 1);
    }
    __syncthreads();
    int v = hist[tid];
    rp[tid] = v;
    __syncthreads();
    for (int off = 1; off < 256; off <<= 1) {
        int t = (tid >= off) ? rp[tid - off] : 0;
        __syncthreads();
        rp[tid] += t;
        __syncthreads();
    }
    int excl = rp[tid] - v;
    cur[tid] = excl;
    int node = (lb << 8) + tid;
    if (node < n_nodes) rowptr[node] = start + excl;
    if (lb == nb - 1 && tid == 0) rowptr[n_nodes] = end;  // = E (layer1) / 2E (layer2)
    __syncthreads();
    for (int i = tid; i < cnt; i += 256) {
        int2 r = rec_in[start + i];
        int rk = atomicAdd(&cur[(r.x >> 20) & 255], 1);
        if (rk < CAP) srec[rk] = r;
    }
    __syncthreads();
    int lim = min(cnt, CAP);
    for (int i = tid; i < lim; i += 256) rec_out[start + i] = srec[i];
}

// ---------------- gather 1 (wave-per-node, 8-wide ILP) + fused relu/gemm2 --------

__global__ __launch_bounds__(256) void gather1_kernel(const __hip_bfloat16* __restrict__ h1,
                                                      const int* __restrict__ rowptr,
                                                      const int2* __restrict__ rec,
                                                      const float* __restrict__ W2,
                                                      float* __restrict__ h2, int n_nodes) {
    __shared__ float W2s[64][17];    // padded: kq groups land on disjoint/2-way banks
    __shared__ float rowbuf[4][64];
    int tid = threadIdx.x;
    for (int i = tid; i < 1024; i += 256) W2s[i >> 4][i & 15] = W2[i];
    int w = tid >> 6, f = tid & 63;
    int n = blockIdx.x * 4 + w;
    bool valid = (n < n_nodes);
    int i = 0, end = 0;
    if (valid) { i = rowptr[n]; end = rowptr[n + 1]; }
    float a0 = 0.f, a1 = 0.f, a2 = 0.f, a3 = 0.f;
    float a4 = 0.f, a5 = 0.f, a6 = 0.f, a7 = 0.f;
    for (; i + 7 < end; i += 8) {
        int2 r0 = rec[i],     r1 = rec[i + 1], r2 = rec[i + 2], r3 = rec[i + 3];
        int2 r4 = rec[i + 4], r5 = rec[i + 5], r6 = rec[i + 6], r7 = rec[i + 7];
        a0 += __bfloat162float(h1[(size_t)(r0.x & 0xFFFFF) * 64 + f]) * __int_as_float(r0.y);
        a1 += __bfloat162float(h1[(size_t)(r1.x & 0xFFFFF) * 64 + f]) * __int_as_float(r1.y);
        a2 += __bfloat162float(h1[(size_t)(r2.x & 0xFFFFF) * 64 + f]) * __int_as_float(r2.y);
        a3 += __bfloat162float(h1[(size_t)(r3.x & 0xFFFFF) * 64 + f]) * __int_as_float(r3.y);
        a4 += __bfloat162float(h1[(size_t)(r4.x & 0xFFFFF) * 64 + f]) * __int_as_float(r4.y);
        a5 += __bfloat162float(h1[(size_t)(r5.x & 0xFFFFF) * 64 + f]) * __int_as_float(r5.y);
        a6 += __bfloat162float(h1[(size_t)(r6.x & 0xFFFFF) * 64 + f]) * __int_as_float(r6.y);
        a7 += __bfloat162float(h1[(size_t)(r7.x & 0xFFFFF) * 64 + f]) * __int_as_float(r7.y);
    }
    for (; i + 3 < end; i += 4) {
        int2 r0 = rec[i], r1 = rec[i + 1], r2 = rec[i + 2], r3 = rec[i + 3];
        a0 += __bfloat162float(h1[(size_t)(r0.x & 0xFFFFF) * 64 + f]) * __int_as_float(r0.y);
        a1 += __bfloat162float(h1[(size_t)(r1.x & 0xFFFFF) * 64 + f]) * __int_as_float(r1.y);
        a2 += __bfloat162float(h1[(size_t)(r2.x & 0xFFFFF) * 64 + f]) * __int_as_float(r2.y);
        a3 += __bfloat162float(h1[(size_t)(r3.x & 0xFFFFF) * 64 + f]) * __int_as_float(r3.y);
    }
    for (; i < end; ++i) {
        int2 r = rec[i];
        a0 += __bfloat162float(h1[(size_t)(r.x & 0xFFFFF) * 64 + f]) * __int_as_float(r.y);
    }
    float r = fmaxf(((a0 + a1) + (a2 + a3)) + ((a4 + a5) + (a6 + a7)), 0.f);  // fused relu
    rowbuf[w][f] = r;
    __syncthreads();   // covers W2s load + all 4 waves' rowbuf writes
    // epilogue = gemm2 row: h2[n][c] = sum_k relu_row[k] * W2[k][c]
    int c = f & 15, kq = f >> 4;
    const float* rb = rowbuf[w];
    float pacc = 0.f;
#pragma unroll
    for (int j = 0; j < 16; ++j) {
        int k = kq * 16 + j;
        pacc += rb[k] * W2s[k][c];   // rb[k] broadcasts within kq-group
    }
    pacc += __shfl_xor(pacc, 16);
    pacc += __shfl_xor(pacc, 32);
    if (valid && f < 16) h2[(size_t)n * 16 + f] = pacc;
}

// ---------------- gather 2 (wave-per-4-nodes, 8-wide ILP) ------------------------

__global__ void gather2_kernel(const float* __restrict__ h2,
                               const int* __restrict__ rowptr,
                               const int2* __restrict__ rec,
                               float* __restrict__ out, int n_nodes) {
    int n = blockIdx.x * 16 + (threadIdx.x >> 4);
    if (n >= n_nodes) return;
    int f = threadIdx.x & 15;
    int i = rowptr[n], end = rowptr[n + 1];
    float a0 = 0.f, a1 = 0.f, a2 = 0.f, a3 = 0.f;
    float a4 = 0.f, a5 = 0.f, a6 = 0.f, a7 = 0.f;
    for (; i + 7 < end; i += 8) {
        int2 r0 = rec[i],     r1 = rec[i + 1], r2 = rec[i + 2], r3 = rec[i + 3];
        int2 r4 = rec[i + 4], r5 = rec[i + 5], r6 = rec[i + 6], r7 = rec[i + 7];
        a0 += h2[(size_t)(r0.x & 0xFFFFF) * 16 + f] * __int_as_float(r0.y);
        a1 += h2[(size_t)(r1.x & 0xFFFFF) * 16 + f] * __int_as_float(r1.y);
        a2 += h2[(size_t)(r2.x & 0xFFFFF) * 16 + f] * __int_as_float(r2.y);
        a3 += h2[(size_t)(r3.x & 0xFFFFF) * 16 + f] * __int_as_float(r3.y);
        a4 += h2[(size_t)(r4.x & 0xFFFFF) * 16 + f] * __int_as_float(r4.y);
        a5 += h2[(size_t)(r5.x & 0xFFFFF) * 16 + f] * __int_as_float(r5.y);
        a6 += h2[(size_t)(r6.x & 0xFFFFF) * 16 + f] * __int_as_float(r6.y);
        a7 += h2[(size_t)(r7.x & 0xFFFFF) * 16 + f] * __int_as_float(r7.y);
    }
    for (; i + 3 < end; i += 4) {
        int2 r0 = rec[i], r1 = rec[i + 1], r2 = rec[i + 2], r3 = rec[i + 3];
        a0 += h2[(size_t)(r0.x & 0xFFFFF) * 16 + f] * __int_as_float(r0.y);
        a1 += h2[(size_t)(r1.x & 0xFFFFF) * 16 + f] * __int_as_float(r1.y);
        a2 += h2[(size_t)(r2.x & 0xFFFFF) * 16 + f] * __int_as_float(r2.y);
        a3 += h2[(size_t)(r3.x & 0xFFFFF) * 16 + f] * __int_as_float(r3.y);
    }
    for (; i < end; ++i) {
        int2 r = rec[i];
        a0 += h2[(size_t)(r.x & 0xFFFFF) * 16 + f] * __int_as_float(r.y);
    }
    out[(size_t)n * 16 + f] = (((a0 + a1) + (a2 + a3)) + ((a4 + a5) + (a6 + a7)));
}

// ---------------- launch ----------------

extern "C" void kernel_launch(void* const* d_in, const int* in_sizes, int n_in,
                              void* d_out, int out_size, void* d_ws, size_t ws_size,
                              hipStream_t stream) {
    const float* x   = (const float*)d_in[0];
    const int*   ei1 = (const int*)d_in[1];
    const int*   ei2 = (const int*)d_in[2];
    const float* ew1 = (const float*)d_in[3];
    const float* ew2 = (const float*)d_in[4];
    const float* W1  = (const float*)d_in[5];
    const float* W2  = (const float*)d_in[6];

    const int n_nodes = in_sizes[0] / 128;          // 100000
    const int n_edges = in_sizes[1] / 2;            // 1600000
    const int nb   = (n_nodes + 255) >> 8;          // 391 buckets per layer
    const int nblk = (n_edges + EPB - 1) / EPB;     // 391 binning blocks per layer
    const int n_scan_tot = 2 * nb * nblk;           // 305762 (both layers)
    const int scan_blocks = (n_scan_tot + 1023) / 1024;  // 299 (<= 512)

    // ws layout:
    //   rec2   : 2E int2  (node-sorted CSR records, both layers)    25.6 MB
    //   recbuf : 2E int2  (bin-sorted intermediate; DEAD after bucket_sort,
    //                      reused for h1 (N*64 bf16) + h2 (N*16 f32))
    //   hist_g : 2*nb*nblk ints, bsums: 512, rowptr1/2: N+1 each
    int2* rec2   = (int2*)d_ws;
    int2* recbuf = rec2 + (size_t)2 * n_edges;
    int*  hist_g = (int*)(recbuf + (size_t)2 * n_edges);
    int*  bsums  = hist_g + n_scan_tot;
    int*  rowptr1 = bsums + 512;
    int*  rowptr2 = rowptr1 + n_nodes + 1;
    __hip_bfloat16* h1 = (__hip_bfloat16*)recbuf;              // N*64 bf16 = 12.8 MB
    float* h2 = (float*)recbuf + (size_t)n_nodes * 32;          // N*16 f32 after h1
    float* out = (float*)d_out;

    // ---- both layers' edge preprocessing (independent of features) ----
    bin_hist_kernel<<<2 * nblk, 256, 0, stream>>>(ei1, ei2, hist_g, n_edges, nblk, nb);
    scan_local_k<<<scan_blocks, 1024, 0, stream>>>(hist_g, bsums, n_scan_tot);
    scan_top_k<<<1, 512, 0, stream>>>(bsums, scan_blocks);
    add_offsets_k<<<scan_blocks, 1024, 0, stream>>>(hist_g, bsums, n_scan_tot);
    bin_scatter_kernel<<<2 * nblk, 256, 0, stream>>>(ei1, ei2, ew1, ew2, hist_g, recbuf,
                                                     n_edges, nblk, nb);
    bucket_sort_kernel<<<2 * nb, 256, 0, stream>>>(recbuf, hist_g, rec2, rowptr1, rowptr2,
                                                   n_nodes, n_edges, nblk, nb);

    // ---- dense + aggregation (recbuf now dead -> h1/h2 live there) ----
    gemm1_kernel<<<(n_nodes + 127) / 128, 128, 0, stream>>>(x, W1, h1, n_nodes);
    gather1_kernel<<<(n_nodes + 3) / 4, 256, 0, stream>>>(h1, rowptr1, rec2, W2, h2, n_nodes);
    gather2_kernel<<<(n_nodes + 15) / 16, 256, 0, stream>>>(h2, rowptr2, rec2, out, n_nodes);
}

// Round 10
// 335.986 us; speedup vs baseline: 1.1449x; 1.0547x over previous
//
#include <hip/hip_runtime.h>
#include <hip/hip_bf16.h>

// GCN 2-layer, fp32 I/O. Pipeline:
//   [both layers up front] bin_hist/scan/bin_scatter (bucket = dst>>8, layer-major
//        concatenated scan -> layer-2 records land at offset E automatically)
//        -> bucket_sort (in-LDS counting sort by dst&255 -> dst-sorted CSR + rowptr)
//   gemm1 (register-tiled fp32 -> bf16 h1, written over the dead recbuf region)
//   gather1 (wave-per-node, 8-wide ILP) FUSED with relu + gemm2 epilogue,
//        fully WAVE-LOCAL: row values shared via __shfl (bpermute), W2 read from
//        global (L1-resident) -> zero __syncthreads, no inter-wave imbalance.
//   gather2 (wave-per-4-nodes, 8-wide ILP)
// Record int2: .x = src | (dst&255)<<20, .y = bits of w.

#define EPB 4096     // edges per binning block
#define NBMAX 512    // max buckets (N <= 131072)
#define CAP 6144     // max records per bucket (avg 4096; 32-sigma headroom)

// ---------------- dense layer 1 (register-tiled, k-major LDS) ----------------

// gemm1: [N,128] @ [128,64] -> bf16 [N,64]. 128 threads, tile 128n x 64f, thread 8x8.
__global__ __launch_bounds__(128) void gemm1_kernel(const float* __restrict__ x,
                                                    const float* __restrict__ W1,
                                                    __hip_bfloat16* __restrict__ h1,
                                                    int n_nodes) {
    __shared__ float As[32][132];   // k-major, node-contiguous; padded
    __shared__ float Bs[32][64];    // k-major, feat-contiguous
    int tid = threadIdx.x;
    int node0 = blockIdx.x * 128;
    int n8 = (tid & 15) * 8;
    int f8 = (tid >> 4) * 8;
    float acc[8][8];
#pragma unroll
    for (int i = 0; i < 8; ++i)
#pragma unroll
        for (int j = 0; j < 8; ++j) acc[i][j] = 0.f;

    const float4* x4 = reinterpret_cast<const float4*>(x);
    const float4* W4 = reinterpret_cast<const float4*>(W1);

    for (int s = 0; s < 4; ++s) {
#pragma unroll
        for (int j = 0; j < 8; ++j) {
            int idx = tid + j * 128;            // 1024 float4 = 128n x 32k
            int n = idx >> 3;
            int kq = idx & 7;
            float4 v = make_float4(0.f, 0.f, 0.f, 0.f);
            if (node0 + n < n_nodes) v = x4[(size_t)(node0 + n) * 32 + s * 8 + kq];
            int k4 = kq * 4;
            As[k4 + 0][n] = v.x;
            As[k4 + 1][n] = v.y;
            As[k4 + 2][n] = v.z;
            As[k4 + 3][n] = v.w;
        }
#pragma unroll
        for (int j = 0; j < 4; ++j) {
            int idx = tid + j * 128;            // 512 float4 = 32k x 64f
            int k = idx >> 4;
            int fq = idx & 15;
            *reinterpret_cast<float4*>(&Bs[k][fq * 4]) = W4[(size_t)(s * 32 + k) * 16 + fq];
        }
        __syncthreads();
#pragma unroll
        for (int kk = 0; kk < 32; ++kk) {
            float4 a0 = *reinterpret_cast<const float4*>(&As[kk][n8]);
            float4 a1 = *reinterpret_cast<const float4*>(&As[kk][n8 + 4]);
            float4 b0 = *reinterpret_cast<const float4*>(&Bs[kk][f8]);
            float4 b1 = *reinterpret_cast<const float4*>(&Bs[kk][f8 + 4]);
            float av[8] = {a0.x, a0.y, a0.z, a0.w, a1.x, a1.y, a1.z, a1.w};
            float bv[8] = {b0.x, b0.y, b0.z, b0.w, b1.x, b1.y, b1.z, b1.w};
#pragma unroll
            for (int i = 0; i < 8; ++i)
#pragma unroll
                for (int j = 0; j < 8; ++j) acc[i][j] += av[i] * bv[j];
        }
        __syncthreads();
    }
#pragma unroll
    for (int i = 0; i < 8; ++i) {
        int n = node0 + n8 + i;
        if (n < n_nodes) {
            __hip_bfloat16 tmp[8];
#pragma unroll
            for (int j = 0; j < 8; ++j) tmp[j] = __float2bfloat16(acc[i][j]);
            *reinterpret_cast<uint4*>(&h1[(size_t)n * 64 + f8]) =
                *reinterpret_cast<const uint4*>(tmp);
        }
    }
}

// ---------------- edge binning, BOTH layers in one pass (bucket = dst>>8) ---------
// hist layout: [layer][bucket][blk] flattened; a single exclusive scan over the
// concatenation yields global record positions in a 2E array: layer 1 in [0,E),
// layer 2 in [E,2E).

__global__ void bin_hist_kernel(const int* __restrict__ ei1, const int* __restrict__ ei2,
                                int* __restrict__ hist_g, int n_edges, int nblk, int nb) {
    __shared__ int hist[NBMAX];
    int tid = threadIdx.x, blk = blockIdx.x;
    int layer = (blk >= nblk) ? 1 : 0;
    int lblk = blk - layer * nblk;
    const int* ei = layer ? ei2 : ei1;
    for (int i = tid; i < nb; i += 256) hist[i] = 0;
    __syncthreads();
    int e0 = lblk * EPB;
#pragma unroll
    for (int j = 0; j < EPB / 256; ++j) {
        int e = e0 + tid + j * 256;
        if (e < n_edges) atomicAdd(&hist[ei[n_edges + e] >> 8], 1);
    }
    __syncthreads();
    int base = layer * nb * nblk;
    for (int i = tid; i < nb; i += 256) hist_g[base + i * nblk + lblk] = hist[i];
}

__global__ void scan_local_k(int* __restrict__ data, int* __restrict__ bsums, int n) {
    __shared__ int tmp[1024];
    int i = blockIdx.x * 1024 + threadIdx.x;
    int v = (i < n) ? data[i] : 0;
    tmp[threadIdx.x] = v;
    __syncthreads();
    for (int off = 1; off < 1024; off <<= 1) {
        int t = (threadIdx.x >= off) ? tmp[threadIdx.x - off] : 0;
        __syncthreads();
        tmp[threadIdx.x] += t;
        __syncthreads();
    }
    if (i < n) data[i] = tmp[threadIdx.x] - v;   // exclusive, in place
    if (threadIdx.x == 1023) bsums[blockIdx.x] = tmp[1023];
}

__global__ void scan_top_k(int* __restrict__ bsums, int nbk) {
    __shared__ int tmp[512];
    int v = (threadIdx.x < nbk) ? bsums[threadIdx.x] : 0;
    tmp[threadIdx.x] = v;
    __syncthreads();
    for (int off = 1; off < 512; off <<= 1) {
        int t = (threadIdx.x >= off) ? tmp[threadIdx.x - off] : 0;
        __syncthreads();
        tmp[threadIdx.x] += t;
        __syncthreads();
    }
    if (threadIdx.x < nbk) bsums[threadIdx.x] = tmp[threadIdx.x] - v;  // exclusive
}

__global__ void add_offsets_k(int* __restrict__ data, const int* __restrict__ bsums, int n) {
    int i = blockIdx.x * 1024 + threadIdx.x;
    if (i < n) data[i] += bsums[blockIdx.x];
}

__global__ void bin_scatter_kernel(const int* __restrict__ ei1, const int* __restrict__ ei2,
                                   const float* __restrict__ ew1, const float* __restrict__ ew2,
                                   const int* __restrict__ scan_g, int2* __restrict__ rec_out,
                                   int n_edges, int nblk, int nb) {
    __shared__ int2 srec[EPB];               // 32 KB
    __shared__ unsigned short sbkt[EPB];     // 8 KB
    __shared__ int loff[NBMAX], cur[NBMAX], gbase[NBMAX];  // 6 KB
    __shared__ int p[256];
    int tid = threadIdx.x, blk = blockIdx.x;
    int layer = (blk >= nblk) ? 1 : 0;
    int lblk = blk - layer * nblk;
    const int* ei = layer ? ei2 : ei1;
    const float* ew = layer ? ew2 : ew1;
    int n_scan_tot = 2 * nb * nblk;
    int total = 2 * n_edges;
    int base = layer * nb * nblk;
    int e0 = lblk * EPB;
    int cnt = min(EPB, n_edges - e0);
    // per-bucket counts for this block, reconstructed from adjacent scan entries
    for (int i = tid; i < nb; i += 256) {
        int l = base + i * nblk + lblk;
        int g = scan_g[l];
        int nxt = (l + 1 < n_scan_tot) ? scan_g[l + 1] : total;
        gbase[i] = g;
        loff[i] = nxt - g;                    // temporarily holds count
    }
    __syncthreads();
    // exclusive scan of counts -> loff (2 buckets/thread + Hillis-Steele over partials)
    int b0 = tid * 2;
    int c0 = (b0 < nb) ? loff[b0] : 0;
    int c1 = (b0 + 1 < nb) ? loff[b0 + 1] : 0;
    p[tid] = c0 + c1;
    __syncthreads();
    for (int off = 1; off < 256; off <<= 1) {
        int t = (tid >= off) ? p[tid - off] : 0;
        __syncthreads();
        p[tid] += t;
        __syncthreads();
    }
    int pbase = (tid > 0) ? p[tid - 1] : 0;
    __syncthreads();
    if (b0 < nb)     { loff[b0] = pbase;          cur[b0] = pbase; }
    if (b0 + 1 < nb) { loff[b0 + 1] = pbase + c0; cur[b0 + 1] = pbase + c0; }
    __syncthreads();
    // rank + stage (LDS counting sort by bucket)
#pragma unroll
    for (int j = 0; j < EPB / 256; ++j) {
        int e = e0 + tid + j * 256;
        if (e < n_edges) {
            int s = ei[e], d = ei[n_edges + e];
            int b = d >> 8;
            int r = atomicAdd(&cur[b], 1);
            srec[r] = make_int2(s | ((d & 255) << 20), __float_as_int(ew[e]));
            sbkt[r] = (unsigned short)b;
        }
    }
    __syncthreads();
    // coalesced run writes
    for (int i = tid; i < cnt; i += 256) {
        int b = sbkt[i];
        rec_out[gbase[b] + (i - loff[b])] = srec[i];
    }
}

// ---------------- per-bucket node sort (-> full CSR + rowptr, both layers) -------

__global__ __launch_bounds__(256) void bucket_sort_kernel(
        const int2* __restrict__ rec_in, const int* __restrict__ scan_g,
        int2* __restrict__ rec_out, int* __restrict__ rowptr1, int* __restrict__ rowptr2,
        int n_nodes, int n_edges, int nblk, int nb) {
    __shared__ int2 srec[CAP];               // 48 KB
    __shared__ int hist[256], cur[256], rp[256];
    int tid = threadIdx.x, b = blockIdx.x;   // global bucket id in [0, 2*nb)
    int layer = (b >= nb) ? 1 : 0;
    int lb = b - layer * nb;
    int* rowptr = layer ? rowptr2 : rowptr1;
    int total = 2 * n_edges;
    int start = scan_g[b * nblk];
    int end = (b + 1 < 2 * nb) ? scan_g[(b + 1) * nblk] : total;
    int cnt = end - start;
    hist[tid] = 0;
    __syncthreads();
    for (int i = tid; i < cnt; i += 256) {
        int2 r = rec_in[start + i];
        atomicAdd(&hist[(r.x >> 20) & 255], 1);
    }
    __syncthreads();
    int v = hist[tid];
    rp[tid] = v;
    __syncthreads();
    for (int off = 1; off < 256; off <<= 1) {
        int t = (tid >= off) ? rp[tid - off] : 0;
        __syncthreads();
        rp[tid] += t;
        __syncthreads();
    }
    int excl = rp[tid] - v;
    cur[tid] = excl;
    int node = (lb << 8) + tid;
    if (node < n_nodes) rowptr[node] = start + excl;
    if (lb == nb - 1 && tid == 0) rowptr[n_nodes] = end;  // = E (layer1) / 2E (layer2)
    __syncthreads();
    for (int i = tid; i < cnt; i += 256) {
        int2 r = rec_in[start + i];
        int rk = atomicAdd(&cur[(r.x >> 20) & 255], 1);
        if (rk < CAP) srec[rk] = r;
    }
    __syncthreads();
    int lim = min(cnt, CAP);
    for (int i = tid; i < lim; i += 256) rec_out[start + i] = srec[i];
}

// ---------------- gather 1 (wave-per-node, 8-wide ILP) + WAVE-LOCAL relu/gemm2 ---
// No __syncthreads anywhere: the 64 relu'd row values live in the wave's 64 lanes;
// the gemm2 row-dot pulls them via __shfl (bpermute). W2 (4 KB) is read straight
// from global memory -> L1-resident after first touch. Waves retire independently,
// so no inter-wave degree-imbalance serialization (the round-5 regression).

__global__ __launch_bounds__(256) void gather1_kernel(const __hip_bfloat16* __restrict__ h1,
                                                      const int* __restrict__ rowptr,
                                                      const int2* __restrict__ rec,
                                                      const float* __restrict__ W2,
                                                      float* __restrict__ h2, int n_nodes) {
    int tid = threadIdx.x;
    int w = tid >> 6, f = tid & 63;
    int n = blockIdx.x * 4 + w;
    bool valid = (n < n_nodes);
    int i = 0, end = 0;
    if (valid) { i = rowptr[n]; end = rowptr[n + 1]; }
    float a0 = 0.f, a1 = 0.f, a2 = 0.f, a3 = 0.f;
    float a4 = 0.f, a5 = 0.f, a6 = 0.f, a7 = 0.f;
    for (; i + 7 < end; i += 8) {
        int2 r0 = rec[i],     r1 = rec[i + 1], r2 = rec[i + 2], r3 = rec[i + 3];
        int2 r4 = rec[i + 4], r5 = rec[i + 5], r6 = rec[i + 6], r7 = rec[i + 7];
        a0 += __bfloat162float(h1[(size_t)(r0.x & 0xFFFFF) * 64 + f]) * __int_as_float(r0.y);
        a1 += __bfloat162float(h1[(size_t)(r1.x & 0xFFFFF) * 64 + f]) * __int_as_float(r1.y);
        a2 += __bfloat162float(h1[(size_t)(r2.x & 0xFFFFF) * 64 + f]) * __int_as_float(r2.y);
        a3 += __bfloat162float(h1[(size_t)(r3.x & 0xFFFFF) * 64 + f]) * __int_as_float(r3.y);
        a4 += __bfloat162float(h1[(size_t)(r4.x & 0xFFFFF) * 64 + f]) * __int_as_float(r4.y);
        a5 += __bfloat162float(h1[(size_t)(r5.x & 0xFFFFF) * 64 + f]) * __int_as_float(r5.y);
        a6 += __bfloat162float(h1[(size_t)(r6.x & 0xFFFFF) * 64 + f]) * __int_as_float(r6.y);
        a7 += __bfloat162float(h1[(size_t)(r7.x & 0xFFFFF) * 64 + f]) * __int_as_float(r7.y);
    }
    for (; i + 3 < end; i += 4) {
        int2 r0 = rec[i], r1 = rec[i + 1], r2 = rec[i + 2], r3 = rec[i + 3];
        a0 += __bfloat162float(h1[(size_t)(r0.x & 0xFFFFF) * 64 + f]) * __int_as_float(r0.y);
        a1 += __bfloat162float(h1[(size_t)(r1.x & 0xFFFFF) * 64 + f]) * __int_as_float(r1.y);
        a2 += __bfloat162float(h1[(size_t)(r2.x & 0xFFFFF) * 64 + f]) * __int_as_float(r2.y);
        a3 += __bfloat162float(h1[(size_t)(r3.x & 0xFFFFF) * 64 + f]) * __int_as_float(r3.y);
    }
    for (; i < end; ++i) {
        int2 r = rec[i];
        a0 += __bfloat162float(h1[(size_t)(r.x & 0xFFFFF) * 64 + f]) * __int_as_float(r.y);
    }
    float r = fmaxf(((a0 + a1) + (a2 + a3)) + ((a4 + a5) + (a6 + a7)), 0.f);  // fused relu
    // epilogue = gemm2 row: h2[n][c] = sum_k relu_row[k] * W2[k][c]
    // lane (16*kq + c) accumulates the kq-th quarter of the k-sum for output col c.
    int c = f & 15, kq = f >> 4;
    float pacc = 0.f;
#pragma unroll
    for (int j = 0; j < 16; ++j) {
        int k = kq * 16 + j;
        float rk = __shfl(r, k, 64);            // row value from lane k (same wave)
        pacc += rk * W2[k * 16 + c];            // 4 KB W2: L1/L2-resident
    }
    pacc += __shfl_xor(pacc, 16, 64);
    pacc += __shfl_xor(pacc, 32, 64);
    if (valid && f < 16) h2[(size_t)n * 16 + f] = pacc;
}

// ---------------- gather 2 (wave-per-4-nodes, 8-wide ILP) ------------------------

__global__ void gather2_kernel(const float* __restrict__ h2,
                               const int* __restrict__ rowptr,
                               const int2* __restrict__ rec,
                               float* __restrict__ out, int n_nodes) {
    int n = blockIdx.x * 16 + (threadIdx.x >> 4);
    if (n >= n_nodes) return;
    int f = threadIdx.x & 15;
    int i = rowptr[n], end = rowptr[n + 1];
    float a0 = 0.f, a1 = 0.f, a2 = 0.f, a3 = 0.f;
    float a4 = 0.f, a5 = 0.f, a6 = 0.f, a7 = 0.f;
    for (; i + 7 < end; i += 8) {
        int2 r0 = rec[i],     r1 = rec[i + 1], r2 = rec[i + 2], r3 = rec[i + 3];
        int2 r4 = rec[i + 4], r5 = rec[i + 5], r6 = rec[i + 6], r7 = rec[i + 7];
        a0 += h2[(size_t)(r0.x & 0xFFFFF) * 16 + f] * __int_as_float(r0.y);
        a1 += h2[(size_t)(r1.x & 0xFFFFF) * 16 + f] * __int_as_float(r1.y);
        a2 += h2[(size_t)(r2.x & 0xFFFFF) * 16 + f] * __int_as_float(r2.y);
        a3 += h2[(size_t)(r3.x & 0xFFFFF) * 16 + f] * __int_as_float(r3.y);
        a4 += h2[(size_t)(r4.x & 0xFFFFF) * 16 + f] * __int_as_float(r4.y);
        a5 += h2[(size_t)(r5.x & 0xFFFFF) * 16 + f] * __int_as_float(r5.y);
        a6 += h2[(size_t)(r6.x & 0xFFFFF) * 16 + f] * __int_as_float(r6.y);
        a7 += h2[(size_t)(r7.x & 0xFFFFF) * 16 + f] * __int_as_float(r7.y);
    }
    for (; i + 3 < end; i += 4) {
        int2 r0 = rec[i], r1 = rec[i + 1], r2 = rec[i + 2], r3 = rec[i + 3];
        a0 += h2[(size_t)(r0.x & 0xFFFFF) * 16 + f] * __int_as_float(r0.y);
        a1 += h2[(size_t)(r1.x & 0xFFFFF) * 16 + f] * __int_as_float(r1.y);
        a2 += h2[(size_t)(r2.x & 0xFFFFF) * 16 + f] * __int_as_float(r2.y);
        a3 += h2[(size_t)(r3.x & 0xFFFFF) * 16 + f] * __int_as_float(r3.y);
    }
    for (; i < end; ++i) {
        int2 r = rec[i];
        a0 += h2[(size_t)(r.x & 0xFFFFF) * 16 + f] * __int_as_float(r.y);
    }
    out[(size_t)n * 16 + f] = (((a0 + a1) + (a2 + a3)) + ((a4 + a5) + (a6 + a7)));
}

// ---------------- launch ----------------

extern "C" void kernel_launch(void* const* d_in, const int* in_sizes, int n_in,
                              void* d_out, int out_size, void* d_ws, size_t ws_size,
                              hipStream_t stream) {
    const float* x   = (const float*)d_in[0];
    const int*   ei1 = (const int*)d_in[1];
    const int*   ei2 = (const int*)d_in[2];
    const float* ew1 = (const float*)d_in[3];
    const float* ew2 = (const float*)d_in[4];
    const float* W1  = (const float*)d_in[5];
    const float* W2  = (const float*)d_in[6];

    const int n_nodes = in_sizes[0] / 128;          // 100000
    const int n_edges = in_sizes[1] / 2;            // 1600000
    const int nb   = (n_nodes + 255) >> 8;          // 391 buckets per layer
    const int nblk = (n_edges + EPB - 1) / EPB;     // 391 binning blocks per layer
    const int n_scan_tot = 2 * nb * nblk;           // 305762 (both layers)
    const int scan_blocks = (n_scan_tot + 1023) / 1024;  // 299 (<= 512)

    // ws layout:
    //   rec2   : 2E int2  (node-sorted CSR records, both layers)    25.6 MB
    //   recbuf : 2E int2  (bin-sorted intermediate; DEAD after bucket_sort,
    //                      reused for h1 (N*64 bf16) + h2 (N*16 f32))
    //   hist_g : 2*nb*nblk ints, bsums: 512, rowptr1/2: N+1 each
    int2* rec2   = (int2*)d_ws;
    int2* recbuf = rec2 + (size_t)2 * n_edges;
    int*  hist_g = (int*)(recbuf + (size_t)2 * n_edges);
    int*  bsums  = hist_g + n_scan_tot;
    int*  rowptr1 = bsums + 512;
    int*  rowptr2 = rowptr1 + n_nodes + 1;
    __hip_bfloat16* h1 = (__hip_bfloat16*)recbuf;              // N*64 bf16 = 12.8 MB
    float* h2 = (float*)recbuf + (size_t)n_nodes * 32;          // N*16 f32 after h1
    float* out = (float*)d_out;

    // ---- both layers' edge preprocessing (independent of features) ----
    bin_hist_kernel<<<2 * nblk, 256, 0, stream>>>(ei1, ei2, hist_g, n_edges, nblk, nb);
    scan_local_k<<<scan_blocks, 1024, 0, stream>>>(hist_g, bsums, n_scan_tot);
    scan_top_k<<<1, 512, 0, stream>>>(bsums, scan_blocks);
    add_offsets_k<<<scan_blocks, 1024, 0, stream>>>(hist_g, bsums, n_scan_tot);
    bin_scatter_kernel<<<2 * nblk, 256, 0, stream>>>(ei1, ei2, ew1, ew2, hist_g, recbuf,
                                                     n_edges, nblk, nb);
    bucket_sort_kernel<<<2 * nb, 256, 0, stream>>>(recbuf, hist_g, rec2, rowptr1, rowptr2,
                                                   n_nodes, n_edges, nblk, nb);

    // ---- dense + aggregation (recbuf now dead -> h1/h2 live there) ----
    gemm1_kernel<<<(n_nodes + 127) / 128, 128, 0, stream>>>(x, W1, h1, n_nodes);
    gather1_kernel<<<(n_nodes + 3) / 4, 256, 0, stream>>>(h1, rowptr1, rec2, W2, h2, n_nodes);
    gather2_kernel<<<(n_nodes + 15) / 16, 256, 0, stream>>>(h2, rowptr2, rec2, out, n_nodes);
}

// Round 12
// 305.168 us; speedup vs baseline: 1.2606x; 1.1010x over previous
//
#include <hip/hip_runtime.h>
#include <hip/hip_bf16.h>

// GCN 2-layer, fp32 I/O. Pipeline:
//   gemm1_hist (MERGED: independent gemm1 + both layers' bin_hist in one dispatch,
//        block-range dispatch -> gemm serialization hidden under binning)
//   scan/bin_scatter (bucket = dst>>8, layer-major concatenated scan -> layer-2
//        records land at offset E automatically)
//   bucket_sort (in-LDS counting sort by dst&255 -> dst-sorted CSR + rowptr)
//   gather1 (wave-per-node, 16/8/4/1-wide ILP) FUSED with wave-local relu+gemm2
//        (row via __shfl, W2 from global/L1; zero __syncthreads)
//   gather2 (wave-per-4-nodes, 8-wide ILP)
// Record int2: .x = src | (dst&255)<<20, .y = bits of w.

#define EPB 4096     // edges per binning block
#define NBMAX 512    // max buckets (N <= 131072)
#define CAP 6144     // max records per bucket (avg 4096; 32-sigma headroom)

// ---------------- merged gemm1 + bin_hist ----------------------------------------
// blocks [0, gemm_blocks): gemm1 [N,128]@[128,64] -> bf16 h1. 256 thr, thread 4x8.
// blocks [gemm_blocks, gemm_blocks+2*nblk): per-4096-edge bucket histograms
// (layer-major [layer][bucket][blk] for the concatenated scan).
__global__ __launch_bounds__(256) void gemm1_hist_kernel(
        const float* __restrict__ x, const float* __restrict__ W1,
        __hip_bfloat16* __restrict__ h1,
        const int* __restrict__ ei1, const int* __restrict__ ei2,
        int* __restrict__ hist_g, int n_nodes, int n_edges, int nblk, int nb,
        int gemm_blocks) {
    __shared__ float As[32][132];   // k-major, node-contiguous; padded (gemm role)
    __shared__ float Bs[32][64];    // k-major, feat-contiguous   (gemm role)
    __shared__ int hist[NBMAX];     // (hist role)
    int tid = threadIdx.x;

    if (blockIdx.x < gemm_blocks) {
        // ---- gemm role ----
        int node0 = blockIdx.x * 128;
        int n4 = (tid & 31) * 4;
        int f8 = (tid >> 5) * 8;
        float acc[4][8];
#pragma unroll
        for (int i = 0; i < 4; ++i)
#pragma unroll
            for (int j = 0; j < 8; ++j) acc[i][j] = 0.f;

        const float4* x4 = reinterpret_cast<const float4*>(x);
        const float4* W4 = reinterpret_cast<const float4*>(W1);

        for (int s = 0; s < 4; ++s) {
#pragma unroll
            for (int j = 0; j < 4; ++j) {
                int idx = tid + j * 256;            // 1024 float4 = 128n x 32k
                int n = idx >> 3;
                int kq = idx & 7;
                float4 v = make_float4(0.f, 0.f, 0.f, 0.f);
                if (node0 + n < n_nodes) v = x4[(size_t)(node0 + n) * 32 + s * 8 + kq];
                int k4 = kq * 4;
                As[k4 + 0][n] = v.x;
                As[k4 + 1][n] = v.y;
                As[k4 + 2][n] = v.z;
                As[k4 + 3][n] = v.w;
            }
#pragma unroll
            for (int j = 0; j < 2; ++j) {
                int idx = tid + j * 256;            // 512 float4 = 32k x 64f
                int k = idx >> 4;
                int fq = idx & 15;
                *reinterpret_cast<float4*>(&Bs[k][fq * 4]) = W4[(size_t)(s * 32 + k) * 16 + fq];
            }
            __syncthreads();
#pragma unroll
            for (int kk = 0; kk < 32; ++kk) {
                float4 a = *reinterpret_cast<const float4*>(&As[kk][n4]);
                float4 b0 = *reinterpret_cast<const float4*>(&Bs[kk][f8]);
                float4 b1 = *reinterpret_cast<const float4*>(&Bs[kk][f8 + 4]);
                float av[4] = {a.x, a.y, a.z, a.w};
                float bv[8] = {b0.x, b0.y, b0.z, b0.w, b1.x, b1.y, b1.z, b1.w};
#pragma unroll
                for (int i = 0; i < 4; ++i)
#pragma unroll
                    for (int j = 0; j < 8; ++j) acc[i][j] += av[i] * bv[j];
            }
            __syncthreads();
        }
#pragma unroll
        for (int i = 0; i < 4; ++i) {
            int n = node0 + n4 + i;
            if (n < n_nodes) {
                __hip_bfloat16 tmp[8];
#pragma unroll
                for (int j = 0; j < 8; ++j) tmp[j] = __float2bfloat16(acc[i][j]);
                *reinterpret_cast<uint4*>(&h1[(size_t)n * 64 + f8]) =
                    *reinterpret_cast<const uint4*>(tmp);
            }
        }
    } else {
        // ---- hist role ----
        int blk = blockIdx.x - gemm_blocks;          // [0, 2*nblk)
        int layer = (blk >= nblk) ? 1 : 0;
        int lblk = blk - layer * nblk;
        const int* ei = layer ? ei2 : ei1;
        for (int i = tid; i < nb; i += 256) hist[i] = 0;
        __syncthreads();
        int e0 = lblk * EPB;
#pragma unroll
        for (int j = 0; j < EPB / 256; ++j) {
            int e = e0 + tid + j * 256;
            if (e < n_edges) atomicAdd(&hist[ei[n_edges + e] >> 8], 1);
        }
        __syncthreads();
        int base = layer * nb * nblk;
        for (int i = tid; i < nb; i += 256) hist_g[base + i * nblk + lblk] = hist[i];
    }
}

__global__ void scan_local_k(int* __restrict__ data, int* __restrict__ bsums, int n) {
    __shared__ int tmp[1024];
    int i = blockIdx.x * 1024 + threadIdx.x;
    int v = (i < n) ? data[i] : 0;
    tmp[threadIdx.x] = v;
    __syncthreads();
    for (int off = 1; off < 1024; off <<= 1) {
        int t = (threadIdx.x >= off) ? tmp[threadIdx.x - off] : 0;
        __syncthreads();
        tmp[threadIdx.x] += t;
        __syncthreads();
    }
    if (i < n) data[i] = tmp[threadIdx.x] - v;   // exclusive, in place
    if (threadIdx.x == 1023) bsums[blockIdx.x] = tmp[1023];
}

__global__ void scan_top_k(int* __restrict__ bsums, int nbk) {
    __shared__ int tmp[512];
    int v = (threadIdx.x < nbk) ? bsums[threadIdx.x] : 0;
    tmp[threadIdx.x] = v;
    __syncthreads();
    for (int off = 1; off < 512; off <<= 1) {
        int t = (threadIdx.x >= off) ? tmp[threadIdx.x - off] : 0;
        __syncthreads();
        tmp[threadIdx.x] += t;
        __syncthreads();
    }
    if (threadIdx.x < nbk) bsums[threadIdx.x] = tmp[threadIdx.x] - v;  // exclusive
}

__global__ void add_offsets_k(int* __restrict__ data, const int* __restrict__ bsums, int n) {
    int i = blockIdx.x * 1024 + threadIdx.x;
    if (i < n) data[i] += bsums[blockIdx.x];
}

__global__ void bin_scatter_kernel(const int* __restrict__ ei1, const int* __restrict__ ei2,
                                   const float* __restrict__ ew1, const float* __restrict__ ew2,
                                   const int* __restrict__ scan_g, int2* __restrict__ rec_out,
                                   int n_edges, int nblk, int nb) {
    __shared__ int2 srec[EPB];               // 32 KB
    __shared__ unsigned short sbkt[EPB];     // 8 KB
    __shared__ int loff[NBMAX], cur[NBMAX], gbase[NBMAX];  // 6 KB
    __shared__ int p[256];
    int tid = threadIdx.x, blk = blockIdx.x;
    int layer = (blk >= nblk) ? 1 : 0;
    int lblk = blk - layer * nblk;
    const int* ei = layer ? ei2 : ei1;
    const float* ew = layer ? ew2 : ew1;
    int n_scan_tot = 2 * nb * nblk;
    int total = 2 * n_edges;
    int base = layer * nb * nblk;
    int e0 = lblk * EPB;
    int cnt = min(EPB, n_edges - e0);
    // per-bucket counts for this block, reconstructed from adjacent scan entries
    for (int i = tid; i < nb; i += 256) {
        int l = base + i * nblk + lblk;
        int g = scan_g[l];
        int nxt = (l + 1 < n_scan_tot) ? scan_g[l + 1] : total;
        gbase[i] = g;
        loff[i] = nxt - g;                    // temporarily holds count
    }
    __syncthreads();
    // exclusive scan of counts -> loff (2 buckets/thread + Hillis-Steele over partials)
    int b0 = tid * 2;
    int c0 = (b0 < nb) ? loff[b0] : 0;
    int c1 = (b0 + 1 < nb) ? loff[b0 + 1] : 0;
    p[tid] = c0 + c1;
    __syncthreads();
    for (int off = 1; off < 256; off <<= 1) {
        int t = (tid >= off) ? p[tid - off] : 0;
        __syncthreads();
        p[tid] += t;
        __syncthreads();
    }
    int pbase = (tid > 0) ? p[tid - 1] : 0;
    __syncthreads();
    if (b0 < nb)     { loff[b0] = pbase;          cur[b0] = pbase; }
    if (b0 + 1 < nb) { loff[b0 + 1] = pbase + c0; cur[b0 + 1] = pbase + c0; }
    __syncthreads();
    // rank + stage (LDS counting sort by bucket)
#pragma unroll
    for (int j = 0; j < EPB / 256; ++j) {
        int e = e0 + tid + j * 256;
        if (e < n_edges) {
            int s = ei[e], d = ei[n_edges + e];
            int b = d >> 8;
            int r = atomicAdd(&cur[b], 1);
            srec[r] = make_int2(s | ((d & 255) << 20), __float_as_int(ew[e]));
            sbkt[r] = (unsigned short)b;
        }
    }
    __syncthreads();
    // coalesced run writes
    for (int i = tid; i < cnt; i += 256) {
        int b = sbkt[i];
        rec_out[gbase[b] + (i - loff[b])] = srec[i];
    }
}

// ---------------- per-bucket node sort (-> full CSR + rowptr, both layers) -------

__global__ __launch_bounds__(256) void bucket_sort_kernel(
        const int2* __restrict__ rec_in, const int* __restrict__ scan_g,
        int2* __restrict__ rec_out, int* __restrict__ rowptr1, int* __restrict__ rowptr2,
        int n_nodes, int n_edges, int nblk, int nb) {
    __shared__ int2 srec[CAP];               // 48 KB
    __shared__ int hist[256], cur[256], rp[256];
    int tid = threadIdx.x, b = blockIdx.x;   // global bucket id in [0, 2*nb)
    int layer = (b >= nb) ? 1 : 0;
    int lb = b - layer * nb;
    int* rowptr = layer ? rowptr2 : rowptr1;
    int total = 2 * n_edges;
    int start = scan_g[b * nblk];
    int end = (b + 1 < 2 * nb) ? scan_g[(b + 1) * nblk] : total;
    int cnt = end - start;
    hist[tid] = 0;
    __syncthreads();
    for (int i = tid; i < cnt; i += 256) {
        int2 r = rec_in[start + i];
        atomicAdd(&hist[(r.x >> 20) & 255], 1);
    }
    __syncthreads();
    int v = hist[tid];
    rp[tid] = v;
    __syncthreads();
    for (int off = 1; off < 256; off <<= 1) {
        int t = (tid >= off) ? rp[tid - off] : 0;
        __syncthreads();
        rp[tid] += t;
        __syncthreads();
    }
    int excl = rp[tid] - v;
    cur[tid] = excl;
    int node = (lb << 8) + tid;
    if (node < n_nodes) rowptr[node] = start + excl;
    if (lb == nb - 1 && tid == 0) rowptr[n_nodes] = end;  // = E (layer1) / 2E (layer2)
    __syncthreads();
    for (int i = tid; i < cnt; i += 256) {
        int2 r = rec_in[start + i];
        int rk = atomicAdd(&cur[(r.x >> 20) & 255], 1);
        if (rk < CAP) srec[rk] = r;
    }
    __syncthreads();
    int lim = min(cnt, CAP);
    for (int i = tid; i < lim; i += 256) rec_out[start + i] = srec[i];
}

// ---------------- gather 1 (wave-per-node, 16/8/4/1-wide) + WAVE-LOCAL relu/gemm2

#define G1_EDGE(rr, aa) \
    aa += __bfloat162float(h1[(size_t)((rr).x & 0xFFFFF) * 64 + f]) * __int_as_float((rr).y)

__global__ __launch_bounds__(256) void gather1_kernel(const __hip_bfloat16* __restrict__ h1,
                                                      const int* __restrict__ rowptr,
                                                      const int2* __restrict__ rec,
                                                      const float* __restrict__ W2,
                                                      float* __restrict__ h2, int n_nodes) {
    int tid = threadIdx.x;
    int w = tid >> 6, f = tid & 63;
    int n = blockIdx.x * 4 + w;
    bool valid = (n < n_nodes);
    int i = 0, end = 0;
    if (valid) { i = rowptr[n]; end = rowptr[n + 1]; }
    float a0 = 0.f, a1 = 0.f, a2 = 0.f, a3 = 0.f;
    float a4 = 0.f, a5 = 0.f, a6 = 0.f, a7 = 0.f;
    float a8 = 0.f, a9 = 0.f, a10 = 0.f, a11 = 0.f;
    float a12 = 0.f, a13 = 0.f, a14 = 0.f, a15 = 0.f;
    for (; i + 15 < end; i += 16) {          // 16-wide: deg>=16 nodes get full MLP
        int2 r0 = rec[i],      r1 = rec[i + 1],  r2 = rec[i + 2],  r3 = rec[i + 3];
        int2 r4 = rec[i + 4],  r5 = rec[i + 5],  r6 = rec[i + 6],  r7 = rec[i + 7];
        int2 r8 = rec[i + 8],  r9 = rec[i + 9],  r10 = rec[i + 10], r11 = rec[i + 11];
        int2 r12 = rec[i + 12], r13 = rec[i + 13], r14 = rec[i + 14], r15 = rec[i + 15];
        G1_EDGE(r0, a0);   G1_EDGE(r1, a1);   G1_EDGE(r2, a2);   G1_EDGE(r3, a3);
        G1_EDGE(r4, a4);   G1_EDGE(r5, a5);   G1_EDGE(r6, a6);   G1_EDGE(r7, a7);
        G1_EDGE(r8, a8);   G1_EDGE(r9, a9);   G1_EDGE(r10, a10); G1_EDGE(r11, a11);
        G1_EDGE(r12, a12); G1_EDGE(r13, a13); G1_EDGE(r14, a14); G1_EDGE(r15, a15);
    }
    for (; i + 7 < end; i += 8) {
        int2 r0 = rec[i],     r1 = rec[i + 1], r2 = rec[i + 2], r3 = rec[i + 3];
        int2 r4 = rec[i + 4], r5 = rec[i + 5], r6 = rec[i + 6], r7 = rec[i + 7];
        G1_EDGE(r0, a0); G1_EDGE(r1, a1); G1_EDGE(r2, a2); G1_EDGE(r3, a3);
        G1_EDGE(r4, a4); G1_EDGE(r5, a5); G1_EDGE(r6, a6); G1_EDGE(r7, a7);
    }
    for (; i + 3 < end; i += 4) {
        int2 r0 = rec[i], r1 = rec[i + 1], r2 = rec[i + 2], r3 = rec[i + 3];
        G1_EDGE(r0, a0); G1_EDGE(r1, a1); G1_EDGE(r2, a2); G1_EDGE(r3, a3);
    }
    for (; i < end; ++i) {
        int2 r = rec[i];
        G1_EDGE(r, a0);
    }
    float s0 = ((a0 + a1) + (a2 + a3)) + ((a4 + a5) + (a6 + a7));
    float s1 = ((a8 + a9) + (a10 + a11)) + ((a12 + a13) + (a14 + a15));
    float r = fmaxf(s0 + s1, 0.f);           // fused relu
    // epilogue = gemm2 row: h2[n][c] = sum_k relu_row[k] * W2[k][c]
    // lane (16*kq + c) accumulates the kq-th quarter of the k-sum for output col c.
    int c = f & 15, kq = f >> 4;
    float pacc = 0.f;
#pragma unroll
    for (int j = 0; j < 16; ++j) {
        int k = kq * 16 + j;
        float rk = __shfl(r, k, 64);            // row value from lane k (same wave)
        pacc += rk * W2[k * 16 + c];            // 4 KB W2: L1/L2-resident
    }
    pacc += __shfl_xor(pacc, 16, 64);
    pacc += __shfl_xor(pacc, 32, 64);
    if (valid && f < 16) h2[(size_t)n * 16 + f] = pacc;
}

// ---------------- gather 2 (wave-per-4-nodes, 8-wide ILP) ------------------------

__global__ void gather2_kernel(const float* __restrict__ h2,
                               const int* __restrict__ rowptr,
                               const int2* __restrict__ rec,
                               float* __restrict__ out, int n_nodes) {
    int n = blockIdx.x * 16 + (threadIdx.x >> 4);
    if (n >= n_nodes) return;
    int f = threadIdx.x & 15;
    int i = rowptr[n], end = rowptr[n + 1];
    float a0 = 0.f, a1 = 0.f, a2 = 0.f, a3 = 0.f;
    float a4 = 0.f, a5 = 0.f, a6 = 0.f, a7 = 0.f;
    for (; i + 7 < end; i += 8) {
        int2 r0 = rec[i],     r1 = rec[i + 1], r2 = rec[i + 2], r3 = rec[i + 3];
        int2 r4 = rec[i + 4], r5 = rec[i + 5], r6 = rec[i + 6], r7 = rec[i + 7];
        a0 += h2[(size_t)(r0.x & 0xFFFFF) * 16 + f] * __int_as_float(r0.y);
        a1 += h2[(size_t)(r1.x & 0xFFFFF) * 16 + f] * __int_as_float(r1.y);
        a2 += h2[(size_t)(r2.x & 0xFFFFF) * 16 + f] * __int_as_float(r2.y);
        a3 += h2[(size_t)(r3.x & 0xFFFFF) * 16 + f] * __int_as_float(r3.y);
        a4 += h2[(size_t)(r4.x & 0xFFFFF) * 16 + f] * __int_as_float(r4.y);
        a5 += h2[(size_t)(r5.x & 0xFFFFF) * 16 + f] * __int_as_float(r5.y);
        a6 += h2[(size_t)(r6.x & 0xFFFFF) * 16 + f] * __int_as_float(r6.y);
        a7 += h2[(size_t)(r7.x & 0xFFFFF) * 16 + f] * __int_as_float(r7.y);
    }
    for (; i + 3 < end; i += 4) {
        int2 r0 = rec[i], r1 = rec[i + 1], r2 = rec[i + 2], r3 = rec[i + 3];
        a0 += h2[(size_t)(r0.x & 0xFFFFF) * 16 + f] * __int_as_float(r0.y);
        a1 += h2[(size_t)(r1.x & 0xFFFFF) * 16 + f] * __int_as_float(r1.y);
        a2 += h2[(size_t)(r2.x & 0xFFFFF) * 16 + f] * __int_as_float(r2.y);
        a3 += h2[(size_t)(r3.x & 0xFFFFF) * 16 + f] * __int_as_float(r3.y);
    }
    for (; i < end; ++i) {
        int2 r = rec[i];
        a0 += h2[(size_t)(r.x & 0xFFFFF) * 16 + f] * __int_as_float(r.y);
    }
    out[(size_t)n * 16 + f] = (((a0 + a1) + (a2 + a3)) + ((a4 + a5) + (a6 + a7)));
}

// ---------------- launch ----------------

extern "C" void kernel_launch(void* const* d_in, const int* in_sizes, int n_in,
                              void* d_out, int out_size, void* d_ws, size_t ws_size,
                              hipStream_t stream) {
    const float* x   = (const float*)d_in[0];
    const int*   ei1 = (const int*)d_in[1];
    const int*   ei2 = (const int*)d_in[2];
    const float* ew1 = (const float*)d_in[3];
    const float* ew2 = (const float*)d_in[4];
    const float* W1  = (const float*)d_in[5];
    const float* W2  = (const float*)d_in[6];

    const int n_nodes = in_sizes[0] / 128;          // 100000
    const int n_edges = in_sizes[1] / 2;            // 1600000
    const int nb   = (n_nodes + 255) >> 8;          // 391 buckets per layer
    const int nblk = (n_edges + EPB - 1) / EPB;     // 391 binning blocks per layer
    const int n_scan_tot = 2 * nb * nblk;           // 305762 (both layers)
    const int scan_blocks = (n_scan_tot + 1023) / 1024;  // 299 (<= 512)
    const int gemm_blocks = (n_nodes + 127) / 128;  // 782

    // ws layout (~66 MB total):
    //   rec2   : 2E int2  (node-sorted CSR records, both layers)    25.6 MB
    //   recbuf : 2E int2  (bin-sorted intermediate; dead after bucket_sort,
    //                      reused for h2 only)                      25.6 MB
    //   hist_g : 2*nb*nblk ints (1.2 MB), bsums: 512, rowptr1/2: N+1 each (0.8 MB)
    //   h1     : N*64 bf16 (12.8 MB) -- placed AFTER rowptr2; must NOT alias
    //            recbuf because gemm1 (merged) writes h1 BEFORE bin_scatter
    //            overwrites recbuf.
    int2* rec2   = (int2*)d_ws;
    int2* recbuf = rec2 + (size_t)2 * n_edges;
    int*  hist_g = (int*)(recbuf + (size_t)2 * n_edges);
    int*  bsums  = hist_g + n_scan_tot;
    int*  rowptr1 = bsums + 512;
    int*  rowptr2 = rowptr1 + n_nodes + 1;
    __hip_bfloat16* h1 = (__hip_bfloat16*)(rowptr2 + n_nodes + 1);  // N*64 bf16
    float* h2 = (float*)recbuf;                                     // recbuf dead by then
    float* out = (float*)d_out;

    // ---- phase 1: gemm1 (independent) merged with both layers' bin_hist ----
    gemm1_hist_kernel<<<gemm_blocks + 2 * nblk, 256, 0, stream>>>(
        x, W1, h1, ei1, ei2, hist_g, n_nodes, n_edges, nblk, nb, gemm_blocks);
    scan_local_k<<<scan_blocks, 1024, 0, stream>>>(hist_g, bsums, n_scan_tot);
    scan_top_k<<<1, 512, 0, stream>>>(bsums, scan_blocks);
    add_offsets_k<<<scan_blocks, 1024, 0, stream>>>(hist_g, bsums, n_scan_tot);
    bin_scatter_kernel<<<2 * nblk, 256, 0, stream>>>(ei1, ei2, ew1, ew2, hist_g, recbuf,
                                                     n_edges, nblk, nb);
    bucket_sort_kernel<<<2 * nb, 256, 0, stream>>>(recbuf, hist_g, rec2, rowptr1, rowptr2,
                                                   n_nodes, n_edges, nblk, nb);

    // ---- aggregation (recbuf now dead -> h2 lives there) ----
    gather1_kernel<<<(n_nodes + 3) / 4, 256, 0, stream>>>(h1, rowptr1, rec2, W2, h2, n_nodes);
    gather2_kernel<<<(n_nodes + 15) / 16, 256, 0, stream>>>(h2, rowptr2, rec2, out, n_nodes);
}

// Round 13
// 297.813 us; speedup vs baseline: 1.2917x; 1.0247x over previous
//
#include <hip/hip_runtime.h>
#include <hip/hip_bf16.h>

// GCN 2-layer, fp32 I/O. Pipeline:
//   gemm1_hist (MERGED: independent gemm1 + both layers' bin_hist in one dispatch)
//   scan/bin_scatter (bucket = dst>>8, layer-major concatenated scan -> layer-2
//        records land at offset E automatically)
//   bucket_sort (in-LDS counting sort by dst&255 -> dst-sorted CSR + rowptr;
//        REWRITES rec.x to a PRE-SCALED BYTE OFFSET: src*128 (L1, h1 bf16 row) or
//        src*64 (L2, h2 f32 row) -- dst bits are dead after sorting)
//   gather1 (wave-per-node, 16/8/4/1-wide ILP, 1-add addressing) FUSED with
//        wave-local relu+gemm2 (row via __shfl, W2 from global/L1; zero barriers)
//   gather2 (wave-per-4-nodes, 8-wide ILP, 1-add addressing)
// Record int2 pre-sort: .x = src | (dst&255)<<20, .y = bits of w.
//        post-sort:     .x = src-row byte offset,  .y = bits of w.

#define EPB 4096     // edges per binning block
#define NBMAX 512    // max buckets (N <= 131072)
#define CAP 6144     // max records per bucket (avg 4096; 32-sigma headroom)

// ---------------- merged gemm1 + bin_hist ----------------------------------------
__global__ __launch_bounds__(256) void gemm1_hist_kernel(
        const float* __restrict__ x, const float* __restrict__ W1,
        __hip_bfloat16* __restrict__ h1,
        const int* __restrict__ ei1, const int* __restrict__ ei2,
        int* __restrict__ hist_g, int n_nodes, int n_edges, int nblk, int nb,
        int gemm_blocks) {
    __shared__ float As[32][132];   // k-major, node-contiguous; padded (gemm role)
    __shared__ float Bs[32][64];    // k-major, feat-contiguous   (gemm role)
    __shared__ int hist[NBMAX];     // (hist role)
    int tid = threadIdx.x;

    if (blockIdx.x < gemm_blocks) {
        // ---- gemm role: [N,128]@[128,64] -> bf16 h1; 256 thr, thread 4x8 ----
        int node0 = blockIdx.x * 128;
        int n4 = (tid & 31) * 4;
        int f8 = (tid >> 5) * 8;
        float acc[4][8];
#pragma unroll
        for (int i = 0; i < 4; ++i)
#pragma unroll
            for (int j = 0; j < 8; ++j) acc[i][j] = 0.f;

        const float4* x4 = reinterpret_cast<const float4*>(x);
        const float4* W4 = reinterpret_cast<const float4*>(W1);

        for (int s = 0; s < 4; ++s) {
#pragma unroll
            for (int j = 0; j < 4; ++j) {
                int idx = tid + j * 256;            // 1024 float4 = 128n x 32k
                int n = idx >> 3;
                int kq = idx & 7;
                float4 v = make_float4(0.f, 0.f, 0.f, 0.f);
                if (node0 + n < n_nodes) v = x4[(size_t)(node0 + n) * 32 + s * 8 + kq];
                int k4 = kq * 4;
                As[k4 + 0][n] = v.x;
                As[k4 + 1][n] = v.y;
                As[k4 + 2][n] = v.z;
                As[k4 + 3][n] = v.w;
            }
#pragma unroll
            for (int j = 0; j < 2; ++j) {
                int idx = tid + j * 256;            // 512 float4 = 32k x 64f
                int k = idx >> 4;
                int fq = idx & 15;
                *reinterpret_cast<float4*>(&Bs[k][fq * 4]) = W4[(size_t)(s * 32 + k) * 16 + fq];
            }
            __syncthreads();
#pragma unroll
            for (int kk = 0; kk < 32; ++kk) {
                float4 a = *reinterpret_cast<const float4*>(&As[kk][n4]);
                float4 b0 = *reinterpret_cast<const float4*>(&Bs[kk][f8]);
                float4 b1 = *reinterpret_cast<const float4*>(&Bs[kk][f8 + 4]);
                float av[4] = {a.x, a.y, a.z, a.w};
                float bv[8] = {b0.x, b0.y, b0.z, b0.w, b1.x, b1.y, b1.z, b1.w};
#pragma unroll
                for (int i = 0; i < 4; ++i)
#pragma unroll
                    for (int j = 0; j < 8; ++j) acc[i][j] += av[i] * bv[j];
            }
            __syncthreads();
        }
#pragma unroll
        for (int i = 0; i < 4; ++i) {
            int n = node0 + n4 + i;
            if (n < n_nodes) {
                __hip_bfloat16 tmp[8];
#pragma unroll
                for (int j = 0; j < 8; ++j) tmp[j] = __float2bfloat16(acc[i][j]);
                *reinterpret_cast<uint4*>(&h1[(size_t)n * 64 + f8]) =
                    *reinterpret_cast<const uint4*>(tmp);
            }
        }
    } else {
        // ---- hist role ----
        int blk = blockIdx.x - gemm_blocks;          // [0, 2*nblk)
        int layer = (blk >= nblk) ? 1 : 0;
        int lblk = blk - layer * nblk;
        const int* ei = layer ? ei2 : ei1;
        for (int i = tid; i < nb; i += 256) hist[i] = 0;
        __syncthreads();
        int e0 = lblk * EPB;
#pragma unroll
        for (int j = 0; j < EPB / 256; ++j) {
            int e = e0 + tid + j * 256;
            if (e < n_edges) atomicAdd(&hist[ei[n_edges + e] >> 8], 1);
        }
        __syncthreads();
        int base = layer * nb * nblk;
        for (int i = tid; i < nb; i += 256) hist_g[base + i * nblk + lblk] = hist[i];
    }
}

__global__ void scan_local_k(int* __restrict__ data, int* __restrict__ bsums, int n) {
    __shared__ int tmp[1024];
    int i = blockIdx.x * 1024 + threadIdx.x;
    int v = (i < n) ? data[i] : 0;
    tmp[threadIdx.x] = v;
    __syncthreads();
    for (int off = 1; off < 1024; off <<= 1) {
        int t = (threadIdx.x >= off) ? tmp[threadIdx.x - off] : 0;
        __syncthreads();
        tmp[threadIdx.x] += t;
        __syncthreads();
    }
    if (i < n) data[i] = tmp[threadIdx.x] - v;   // exclusive, in place
    if (threadIdx.x == 1023) bsums[blockIdx.x] = tmp[1023];
}

__global__ void scan_top_k(int* __restrict__ bsums, int nbk) {
    __shared__ int tmp[512];
    int v = (threadIdx.x < nbk) ? bsums[threadIdx.x] : 0;
    tmp[threadIdx.x] = v;
    __syncthreads();
    for (int off = 1; off < 512; off <<= 1) {
        int t = (threadIdx.x >= off) ? tmp[threadIdx.x - off] : 0;
        __syncthreads();
        tmp[threadIdx.x] += t;
        __syncthreads();
    }
    if (threadIdx.x < nbk) bsums[threadIdx.x] = tmp[threadIdx.x] - v;  // exclusive
}

__global__ void add_offsets_k(int* __restrict__ data, const int* __restrict__ bsums, int n) {
    int i = blockIdx.x * 1024 + threadIdx.x;
    if (i < n) data[i] += bsums[blockIdx.x];
}

__global__ void bin_scatter_kernel(const int* __restrict__ ei1, const int* __restrict__ ei2,
                                   const float* __restrict__ ew1, const float* __restrict__ ew2,
                                   const int* __restrict__ scan_g, int2* __restrict__ rec_out,
                                   int n_edges, int nblk, int nb) {
    __shared__ int2 srec[EPB];               // 32 KB
    __shared__ unsigned short sbkt[EPB];     // 8 KB
    __shared__ int loff[NBMAX], cur[NBMAX], gbase[NBMAX];  // 6 KB
    __shared__ int p[256];
    int tid = threadIdx.x, blk = blockIdx.x;
    int layer = (blk >= nblk) ? 1 : 0;
    int lblk = blk - layer * nblk;
    const int* ei = layer ? ei2 : ei1;
    const float* ew = layer ? ew2 : ew1;
    int n_scan_tot = 2 * nb * nblk;
    int total = 2 * n_edges;
    int base = layer * nb * nblk;
    int e0 = lblk * EPB;
    int cnt = min(EPB, n_edges - e0);
    // per-bucket counts for this block, reconstructed from adjacent scan entries
    for (int i = tid; i < nb; i += 256) {
        int l = base + i * nblk + lblk;
        int g = scan_g[l];
        int nxt = (l + 1 < n_scan_tot) ? scan_g[l + 1] : total;
        gbase[i] = g;
        loff[i] = nxt - g;                    // temporarily holds count
    }
    __syncthreads();
    // exclusive scan of counts -> loff (2 buckets/thread + Hillis-Steele over partials)
    int b0 = tid * 2;
    int c0 = (b0 < nb) ? loff[b0] : 0;
    int c1 = (b0 + 1 < nb) ? loff[b0 + 1] : 0;
    p[tid] = c0 + c1;
    __syncthreads();
    for (int off = 1; off < 256; off <<= 1) {
        int t = (tid >= off) ? p[tid - off] : 0;
        __syncthreads();
        p[tid] += t;
        __syncthreads();
    }
    int pbase = (tid > 0) ? p[tid - 1] : 0;
    __syncthreads();
    if (b0 < nb)     { loff[b0] = pbase;          cur[b0] = pbase; }
    if (b0 + 1 < nb) { loff[b0 + 1] = pbase + c0; cur[b0 + 1] = pbase + c0; }
    __syncthreads();
    // rank + stage (LDS counting sort by bucket)
#pragma unroll
    for (int j = 0; j < EPB / 256; ++j) {
        int e = e0 + tid + j * 256;
        if (e < n_edges) {
            int s = ei[e], d = ei[n_edges + e];
            int b = d >> 8;
            int r = atomicAdd(&cur[b], 1);
            srec[r] = make_int2(s | ((d & 255) << 20), __float_as_int(ew[e]));
            sbkt[r] = (unsigned short)b;
        }
    }
    __syncthreads();
    // coalesced run writes
    for (int i = tid; i < cnt; i += 256) {
        int b = sbkt[i];
        rec_out[gbase[b] + (i - loff[b])] = srec[i];
    }
}

// ---------------- per-bucket node sort (-> full CSR + rowptr, both layers) -------
// On output, rec.x is rewritten to the gather-side BYTE OFFSET of the src row:
//   layer 1: src*128 (h1 row = 64 bf16), layer 2: src*64 (h2 row = 16 f32).
// The dst bits are consumed here (rank) and dead afterwards.

__global__ __launch_bounds__(256) void bucket_sort_kernel(
        const int2* __restrict__ rec_in, const int* __restrict__ scan_g,
        int2* __restrict__ rec_out, int* __restrict__ rowptr1, int* __restrict__ rowptr2,
        int n_nodes, int n_edges, int nblk, int nb) {
    __shared__ int2 srec[CAP];               // 48 KB
    __shared__ int hist[256], cur[256], rp[256];
    int tid = threadIdx.x, b = blockIdx.x;   // global bucket id in [0, 2*nb)
    int layer = (b >= nb) ? 1 : 0;
    int lb = b - layer * nb;
    int* rowptr = layer ? rowptr2 : rowptr1;
    int sh = layer ? 6 : 7;                  // byte-offset shift for this layer
    int total = 2 * n_edges;
    int start = scan_g[b * nblk];
    int end = (b + 1 < 2 * nb) ? scan_g[(b + 1) * nblk] : total;
    int cnt = end - start;
    hist[tid] = 0;
    __syncthreads();
    for (int i = tid; i < cnt; i += 256) {
        int2 r = rec_in[start + i];
        atomicAdd(&hist[(r.x >> 20) & 255], 1);
    }
    __syncthreads();
    int v = hist[tid];
    rp[tid] = v;
    __syncthreads();
    for (int off = 1; off < 256; off <<= 1) {
        int t = (tid >= off) ? rp[tid - off] : 0;
        __syncthreads();
        rp[tid] += t;
        __syncthreads();
    }
    int excl = rp[tid] - v;
    cur[tid] = excl;
    int node = (lb << 8) + tid;
    if (node < n_nodes) rowptr[node] = start + excl;
    if (lb == nb - 1 && tid == 0) rowptr[n_nodes] = end;  // = E (layer1) / 2E (layer2)
    __syncthreads();
    for (int i = tid; i < cnt; i += 256) {
        int2 r = rec_in[start + i];
        int rk = atomicAdd(&cur[(r.x >> 20) & 255], 1);
        r.x = (r.x & 0xFFFFF) << sh;          // -> pre-scaled byte offset
        if (rk < CAP) srec[rk] = r;
    }
    __syncthreads();
    int lim = min(cnt, CAP);
    for (int i = tid; i < lim; i += 256) rec_out[start + i] = srec[i];
}

// ---------------- gather 1 (wave-per-node, 16/8/4/1-wide) + WAVE-LOCAL relu/gemm2
// rec.x is a byte offset -> per-edge addressing is ONE v_add.

#define G1_EDGE(rr, aa) \
    aa += __bfloat162float(*(const __hip_bfloat16*)(h1b + (unsigned)(rr).x + f2)) * \
          __int_as_float((rr).y)

__global__ __launch_bounds__(256) void gather1_kernel(const __hip_bfloat16* __restrict__ h1,
                                                      const int* __restrict__ rowptr,
                                                      const int2* __restrict__ rec,
                                                      const float* __restrict__ W2,
                                                      float* __restrict__ h2, int n_nodes) {
    int tid = threadIdx.x;
    int w = tid >> 6, f = tid & 63;
    unsigned f2 = (unsigned)(f << 1);
    const char* h1b = (const char*)h1;
    int n = blockIdx.x * 4 + w;
    bool valid = (n < n_nodes);
    int i = 0, end = 0;
    if (valid) { i = rowptr[n]; end = rowptr[n + 1]; }
    float a0 = 0.f, a1 = 0.f, a2 = 0.f, a3 = 0.f;
    float a4 = 0.f, a5 = 0.f, a6 = 0.f, a7 = 0.f;
    float a8 = 0.f, a9 = 0.f, a10 = 0.f, a11 = 0.f;
    float a12 = 0.f, a13 = 0.f, a14 = 0.f, a15 = 0.f;
    for (; i + 15 < end; i += 16) {          // 16-wide: deg>=16 nodes get full MLP
        int2 r0 = rec[i],      r1 = rec[i + 1],  r2 = rec[i + 2],  r3 = rec[i + 3];
        int2 r4 = rec[i + 4],  r5 = rec[i + 5],  r6 = rec[i + 6],  r7 = rec[i + 7];
        int2 r8 = rec[i + 8],  r9 = rec[i + 9],  r10 = rec[i + 10], r11 = rec[i + 11];
        int2 r12 = rec[i + 12], r13 = rec[i + 13], r14 = rec[i + 14], r15 = rec[i + 15];
        G1_EDGE(r0, a0);   G1_EDGE(r1, a1);   G1_EDGE(r2, a2);   G1_EDGE(r3, a3);
        G1_EDGE(r4, a4);   G1_EDGE(r5, a5);   G1_EDGE(r6, a6);   G1_EDGE(r7, a7);
        G1_EDGE(r8, a8);   G1_EDGE(r9, a9);   G1_EDGE(r10, a10); G1_EDGE(r11, a11);
        G1_EDGE(r12, a12); G1_EDGE(r13, a13); G1_EDGE(r14, a14); G1_EDGE(r15, a15);
    }
    for (; i + 7 < end; i += 8) {
        int2 r0 = rec[i],     r1 = rec[i + 1], r2 = rec[i + 2], r3 = rec[i + 3];
        int2 r4 = rec[i + 4], r5 = rec[i + 5], r6 = rec[i + 6], r7 = rec[i + 7];
        G1_EDGE(r0, a0); G1_EDGE(r1, a1); G1_EDGE(r2, a2); G1_EDGE(r3, a3);
        G1_EDGE(r4, a4); G1_EDGE(r5, a5); G1_EDGE(r6, a6); G1_EDGE(r7, a7);
    }
    for (; i + 3 < end; i += 4) {
        int2 r0 = rec[i], r1 = rec[i + 1], r2 = rec[i + 2], r3 = rec[i + 3];
        G1_EDGE(r0, a0); G1_EDGE(r1, a1); G1_EDGE(r2, a2); G1_EDGE(r3, a3);
    }
    for (; i < end; ++i) {
        int2 r = rec[i];
        G1_EDGE(r, a0);
    }
    float s0 = ((a0 + a1) + (a2 + a3)) + ((a4 + a5) + (a6 + a7));
    float s1 = ((a8 + a9) + (a10 + a11)) + ((a12 + a13) + (a14 + a15));
    float r = fmaxf(s0 + s1, 0.f);           // fused relu
    // epilogue = gemm2 row: h2[n][c] = sum_k relu_row[k] * W2[k][c]
    // lane (16*kq + c) accumulates the kq-th quarter of the k-sum for output col c.
    int c = f & 15, kq = f >> 4;
    float pacc = 0.f;
#pragma unroll
    for (int j = 0; j < 16; ++j) {
        int k = kq * 16 + j;
        float rk = __shfl(r, k, 64);            // row value from lane k (same wave)
        pacc += rk * W2[k * 16 + c];            // 4 KB W2: L1/L2-resident
    }
    pacc += __shfl_xor(pacc, 16, 64);
    pacc += __shfl_xor(pacc, 32, 64);
    if (valid && f < 16) h2[(size_t)n * 16 + f] = pacc;
}

// ---------------- gather 2 (wave-per-4-nodes, 8-wide ILP, 1-add addressing) ------

#define G2_EDGE(rr, aa) \
    aa += *(const float*)(h2b + (unsigned)(rr).x + f4) * __int_as_float((rr).y)

__global__ void gather2_kernel(const float* __restrict__ h2,
                               const int* __restrict__ rowptr,
                               const int2* __restrict__ rec,
                               float* __restrict__ out, int n_nodes) {
    int n = blockIdx.x * 16 + (threadIdx.x >> 4);
    if (n >= n_nodes) return;
    int f = threadIdx.x & 15;
    unsigned f4 = (unsigned)(f << 2);
    const char* h2b = (const char*)h2;
    int i = rowptr[n], end = rowptr[n + 1];
    float a0 = 0.f, a1 = 0.f, a2 = 0.f, a3 = 0.f;
    float a4 = 0.f, a5 = 0.f, a6 = 0.f, a7 = 0.f;
    for (; i + 7 < end; i += 8) {
        int2 r0 = rec[i],     r1 = rec[i + 1], r2 = rec[i + 2], r3 = rec[i + 3];
        int2 r4 = rec[i + 4], r5 = rec[i + 5], r6 = rec[i + 6], r7 = rec[i + 7];
        G2_EDGE(r0, a0); G2_EDGE(r1, a1); G2_EDGE(r2, a2); G2_EDGE(r3, a3);
        G2_EDGE(r4, a4); G2_EDGE(r5, a5); G2_EDGE(r6, a6); G2_EDGE(r7, a7);
    }
    for (; i + 3 < end; i += 4) {
        int2 r0 = rec[i], r1 = rec[i + 1], r2 = rec[i + 2], r3 = rec[i + 3];
        G2_EDGE(r0, a0); G2_EDGE(r1, a1); G2_EDGE(r2, a2); G2_EDGE(r3, a3);
    }
    for (; i < end; ++i) {
        int2 r = rec[i];
        G2_EDGE(r, a0);
    }
    out[(size_t)n * 16 + f] = (((a0 + a1) + (a2 + a3)) + ((a4 + a5) + (a6 + a7)));
}

// ---------------- launch ----------------

extern "C" void kernel_launch(void* const* d_in, const int* in_sizes, int n_in,
                              void* d_out, int out_size, void* d_ws, size_t ws_size,
                              hipStream_t stream) {
    const float* x   = (const float*)d_in[0];
    const int*   ei1 = (const int*)d_in[1];
    const int*   ei2 = (const int*)d_in[2];
    const float* ew1 = (const float*)d_in[3];
    const float* ew2 = (const float*)d_in[4];
    const float* W1  = (const float*)d_in[5];
    const float* W2  = (const float*)d_in[6];

    const int n_nodes = in_sizes[0] / 128;          // 100000
    const int n_edges = in_sizes[1] / 2;            // 1600000
    const int nb   = (n_nodes + 255) >> 8;          // 391 buckets per layer
    const int nblk = (n_edges + EPB - 1) / EPB;     // 391 binning blocks per layer
    const int n_scan_tot = 2 * nb * nblk;           // 305762 (both layers)
    const int scan_blocks = (n_scan_tot + 1023) / 1024;  // 299 (<= 512)
    const int gemm_blocks = (n_nodes + 127) / 128;  // 782

    // ws layout (~66 MB total):
    //   rec2   : 2E int2  (node-sorted CSR records, both layers)    25.6 MB
    //   recbuf : 2E int2  (bin-sorted intermediate; dead after bucket_sort,
    //                      reused for h2 only)                      25.6 MB
    //   hist_g : 2*nb*nblk ints (1.2 MB), bsums: 512, rowptr1/2: N+1 each (0.8 MB)
    //   h1     : N*64 bf16 (12.8 MB) -- placed AFTER rowptr2; must NOT alias
    //            recbuf because gemm1 (merged) writes h1 BEFORE bin_scatter
    //            overwrites recbuf.
    int2* rec2   = (int2*)d_ws;
    int2* recbuf = rec2 + (size_t)2 * n_edges;
    int*  hist_g = (int*)(recbuf + (size_t)2 * n_edges);
    int*  bsums  = hist_g + n_scan_tot;
    int*  rowptr1 = bsums + 512;
    int*  rowptr2 = rowptr1 + n_nodes + 1;
    __hip_bfloat16* h1 = (__hip_bfloat16*)(rowptr2 + n_nodes + 1);  // N*64 bf16
    float* h2 = (float*)recbuf;                                     // recbuf dead by then
    float* out = (float*)d_out;

    // ---- phase 1: gemm1 (independent) merged with both layers' bin_hist ----
    gemm1_hist_kernel<<<gemm_blocks + 2 * nblk, 256, 0, stream>>>(
        x, W1, h1, ei1, ei2, hist_g, n_nodes, n_edges, nblk, nb, gemm_blocks);
    scan_local_k<<<scan_blocks, 1024, 0, stream>>>(hist_g, bsums, n_scan_tot);
    scan_top_k<<<1, 512, 0, stream>>>(bsums, scan_blocks);
    add_offsets_k<<<scan_blocks, 1024, 0, stream>>>(hist_g, bsums, n_scan_tot);
    bin_scatter_kernel<<<2 * nblk, 256, 0, stream>>>(ei1, ei2, ew1, ew2, hist_g, recbuf,
                                                     n_edges, nblk, nb);
    bucket_sort_kernel<<<2 * nb, 256, 0, stream>>>(recbuf, hist_g, rec2, rowptr1, rowptr2,
                                                   n_nodes, n_edges, nblk, nb);

    // ---- aggregation (recbuf now dead -> h2 lives there) ----
    gather1_kernel<<<(n_nodes + 3) / 4, 256, 0, stream>>>(h1, rowptr1, rec2, W2, h2, n_nodes);
    gather2_kernel<<<(n_nodes + 15) / 16, 256, 0, stream>>>(h2, rowptr2, rec2, out, n_nodes);
}